// Round 1
// baseline (6087.251 us; speedup 1.0000x reference)
//
#include <hip/hip_runtime.h>

// ---------------------------------------------------------------------------
// EGNN layer, f32 correctness-first implementation.
// Edge kernel: thread-per-edge, weights via uniform (scalar) loads,
// activation ping-pong through padded LDS rows to avoid scratch.
// Node kernel: wave-per-node, W_n staged in LDS, shfl-based LN.
// ---------------------------------------------------------------------------

__global__ __launch_bounds__(128) void egnn_edge(
    const float* __restrict__ h, const float* __restrict__ pos,
    const int* __restrict__ ei, const float* __restrict__ ea,
    const float* __restrict__ We1, const float* __restrict__ be1,
    const float* __restrict__ We2, const float* __restrict__ be2,
    const float* __restrict__ Wc1, const float* __restrict__ bc1,
    const float* __restrict__ Wc2, const float* __restrict__ bc2,
    float* __restrict__ agg, float* __restrict__ dpos, int E)
{
    __shared__ float lds[128 * 65];   // per-thread padded row (65 -> conflict-free)
    const int e = blockIdx.x * 128 + threadIdx.x;
    if (e >= E) return;

    const int src = ei[e];
    const int dst = ei[E + e];

    const float psx = pos[3 * src + 0], psy = pos[3 * src + 1], psz = pos[3 * src + 2];
    const float pdx = pos[3 * dst + 0], pdy = pos[3 * dst + 1], pdz = pos[3 * dst + 2];
    const float dx = pdx - psx, dy = pdy - psy, dz = pdz - psz;
    float d2 = dx * dx + dy * dy + dz * dz;
    d2 = fminf(d2, 1000.0f);                       // clip(d2, 0, 1000)
    const float inv = 1.0f / sqrtf(d2 + 1e-8f);    // direction scale

    // ---- layer 1: m1 = relu(x @ We1 + be1), x = [h_src, h_dst, d2, ea] ----
    float m1[64];
    #pragma unroll
    for (int j = 0; j < 64; ++j) m1[j] = be1[j];

    const float4* __restrict__ hs4 = reinterpret_cast<const float4*>(h + (size_t)src * 64);
    const float4* __restrict__ hd4 = reinterpret_cast<const float4*>(h + (size_t)dst * 64);

    #pragma unroll 2
    for (int k4 = 0; k4 < 16; ++k4) {
        const float4 a = hs4[k4];
        const float4 b = hd4[k4];
        const float* __restrict__ wa = We1 + (k4 * 4) * 64;        // rows k4*4+u
        const float* __restrict__ wb = We1 + (64 + k4 * 4) * 64;   // rows 64+k4*4+u
        #pragma unroll
        for (int u = 0; u < 4; ++u) {
            const float xa = (&a.x)[u];
            const float xb = (&b.x)[u];
            #pragma unroll
            for (int j = 0; j < 64; ++j) m1[j] = fmaf(xa, wa[u * 64 + j], m1[j]);
            #pragma unroll
            for (int j = 0; j < 64; ++j) m1[j] = fmaf(xb, wb[u * 64 + j], m1[j]);
        }
    }
    {   // dist2 row (k = 128)
        const float* __restrict__ w = We1 + 128 * 64;
        #pragma unroll
        for (int j = 0; j < 64; ++j) m1[j] = fmaf(d2, w[j], m1[j]);
    }
    {   // edge_attr rows (k = 129..144)
        const float4* __restrict__ ea4 = reinterpret_cast<const float4*>(ea + (size_t)e * 16);
        #pragma unroll
        for (int k4 = 0; k4 < 4; ++k4) {
            const float4 a = ea4[k4];
            const float* __restrict__ w = We1 + (129 + k4 * 4) * 64;
            #pragma unroll
            for (int u = 0; u < 4; ++u) {
                const float x = (&a.x)[u];
                #pragma unroll
                for (int j = 0; j < 64; ++j) m1[j] = fmaf(x, w[u * 64 + j], m1[j]);
            }
        }
    }

    const int base = threadIdx.x * 65;
    #pragma unroll
    for (int j = 0; j < 64; ++j) {
        m1[j] = fmaxf(m1[j], 0.0f);
        lds[base + j] = m1[j];       // own row only -> no sync needed
    }

    // ---- layer 2: m2 = relu(m1 @ We2 + be2) ----
    float m2[64];
    #pragma unroll
    for (int j = 0; j < 64; ++j) m2[j] = be2[j];
    #pragma unroll 4
    for (int k = 0; k < 64; ++k) {
        const float xk = lds[base + k];
        const float* __restrict__ w = We2 + k * 64;
        #pragma unroll
        for (int j = 0; j < 64; ++j) m2[j] = fmaf(xk, w[j], m2[j]);
    }
    #pragma unroll
    for (int j = 0; j < 64; ++j) {
        m2[j] = fmaxf(m2[j], 0.0f);
        lds[base + j] = m2[j];
    }

    // ---- coord MLP: c = relu(m2 @ Wc1 + bc1); coef = tanh(c @ Wc2 + bc2)*0.1
    float c[64];
    #pragma unroll
    for (int j = 0; j < 64; ++j) c[j] = bc1[j];
    #pragma unroll 4
    for (int k = 0; k < 64; ++k) {
        const float xk = lds[base + k];
        const float* __restrict__ w = Wc1 + k * 64;
        #pragma unroll
        for (int j = 0; j < 64; ++j) c[j] = fmaf(xk, w[j], c[j]);
    }
    float cacc = bc2[0];
    #pragma unroll
    for (int k = 0; k < 64; ++k) cacc = fmaf(fmaxf(c[k], 0.0f), Wc2[k], cacc);
    const float coef = tanhf(cacc) * 0.1f;

    // ---- scatter ----
    unsafeAtomicAdd(&dpos[3 * dst + 0], dx * inv * coef);
    unsafeAtomicAdd(&dpos[3 * dst + 1], dy * inv * coef);
    unsafeAtomicAdd(&dpos[3 * dst + 2], dz * inv * coef);
    float* __restrict__ arow = agg + (size_t)dst * 64;
    #pragma unroll
    for (int j = 0; j < 64; ++j) unsafeAtomicAdd(&arow[j], m2[j]);
}

__global__ __launch_bounds__(256) void egnn_node(
    const float* __restrict__ h, const float* __restrict__ pos,
    const float* __restrict__ agg, const float* __restrict__ dpos,
    const float* __restrict__ Wn, const float* __restrict__ bn,
    const float* __restrict__ lng, const float* __restrict__ lnb,
    float* __restrict__ h_out, float* __restrict__ pos_out, int N)
{
    __shared__ float sW[128 * 64];   // 32 KiB
    for (int i = threadIdx.x; i < (128 * 64) / 4; i += 256)
        reinterpret_cast<float4*>(sW)[i] = reinterpret_cast<const float4*>(Wn)[i];
    __syncthreads();

    const int lane = threadIdx.x & 63;
    const int wid  = threadIdx.x >> 6;
    const float bnl = bn[lane];
    const float g   = lng[lane];
    const float bb  = lnb[lane];

    for (int i = blockIdx.x * 4 + wid; i < N; i += gridDim.x * 4) {
        const float xh = h[(size_t)i * 64 + lane];
        const float xa = agg[(size_t)i * 64 + lane];
        float acc = bnl;
        #pragma unroll 8
        for (int k = 0; k < 64; ++k)
            acc = fmaf(__shfl(xh, k), sW[k * 64 + lane], acc);
        #pragma unroll 8
        for (int k = 0; k < 64; ++k)
            acc = fmaf(__shfl(xa, k), sW[(64 + k) * 64 + lane], acc);

        const float x = xh + fmaxf(acc, 0.0f);
        float s = x;
        #pragma unroll
        for (int off = 32; off > 0; off >>= 1) s += __shfl_xor(s, off);
        const float mu = s * 0.015625f;
        const float d = x - mu;
        float v = d * d;
        #pragma unroll
        for (int off = 32; off > 0; off >>= 1) v += __shfl_xor(v, off);
        v *= 0.015625f;
        const float ho = d * rsqrtf(v + 1e-5f) * g + bb;
        h_out[(size_t)i * 64 + lane] = ho;

        if (lane < 3) {
            pos_out[(size_t)i * 3 + lane] =
                pos[(size_t)i * 3 + lane] + dpos[(size_t)i * 3 + lane];
        }
    }
}

extern "C" void kernel_launch(void* const* d_in, const int* in_sizes, int n_in,
                              void* d_out, int out_size, void* d_ws, size_t ws_size,
                              hipStream_t stream)
{
    const float* h   = (const float*)d_in[0];
    const float* pos = (const float*)d_in[1];
    const int*   ei  = (const int*)d_in[2];
    const float* ea  = (const float*)d_in[3];
    const float* We1 = (const float*)d_in[4];
    const float* be1 = (const float*)d_in[5];
    const float* We2 = (const float*)d_in[6];
    const float* be2 = (const float*)d_in[7];
    const float* Wc1 = (const float*)d_in[8];
    const float* bc1 = (const float*)d_in[9];
    const float* Wc2 = (const float*)d_in[10];
    const float* bc2 = (const float*)d_in[11];
    const float* Wn  = (const float*)d_in[12];
    const float* bn  = (const float*)d_in[13];
    const float* lng = (const float*)d_in[14];
    const float* lnb = (const float*)d_in[15];

    const int N = in_sizes[0] / 64;
    const int E = in_sizes[2] / 2;

    float* agg  = (float*)d_ws;                 // [N,64]
    float* dpos = agg + (size_t)N * 64;         // [N,3]
    hipMemsetAsync(d_ws, 0, (size_t)N * 67 * sizeof(float), stream);

    float* h_out   = (float*)d_out;             // [N,64]
    float* pos_out = h_out + (size_t)N * 64;    // [N,3]

    const int eblocks = (E + 127) / 128;
    egnn_edge<<<eblocks, 128, 0, stream>>>(h, pos, ei, ea, We1, be1, We2, be2,
                                           Wc1, bc1, Wc2, bc2, agg, dpos, E);
    egnn_node<<<2048, 256, 0, stream>>>(h, pos, agg, dpos, Wn, bn, lng, lnb,
                                        h_out, pos_out, N);
}

// Round 2
// 712.254 us; speedup vs baseline: 8.5465x; 8.5465x over previous
//
#include <hip/hip_runtime.h>

using f32x4  = __attribute__((ext_vector_type(4))) float;
using short8 = __attribute__((ext_vector_type(8))) short;

__device__ inline short f2bf(float x) {
    union { float f; unsigned u; } v; v.f = x;
    unsigned r = v.u + 0x7fffu + ((v.u >> 16) & 1u);   // RNE
    return (short)(r >> 16);
}

__device__ inline short8 pack8(float4 a, float4 b) {
    short8 r;
    r[0] = f2bf(a.x); r[1] = f2bf(a.y); r[2] = f2bf(a.z); r[3] = f2bf(a.w);
    r[4] = f2bf(b.x); r[5] = f2bf(b.y); r[6] = f2bf(b.z); r[7] = f2bf(b.w);
    return r;
}

// ---------------------------------------------------------------------------
// Weight prep: f32 -> bf16, transposed (W^T[n][k]), layer-1 K permuted:
// k 0..127 = h_src,h_dst rows; 128..143 = ea rows (orig 129..144);
// k 144 = dist2 row (orig 128); 145..159 = zero pad.
// ---------------------------------------------------------------------------
__global__ __launch_bounds__(256) void convert_weights(
    const float* __restrict__ We1, const float* __restrict__ We2,
    const float* __restrict__ Wc1,
    short* __restrict__ W1T, short* __restrict__ W2T, short* __restrict__ Wc1T)
{
    const int i = blockIdx.x * 256 + threadIdx.x;
    if (i < 64 * 160) {
        const int n = i / 160, k = i % 160;
        float v = 0.0f;
        if (k < 128)       v = We1[k * 64 + n];
        else if (k < 144)  v = We1[(129 + k - 128) * 64 + n];
        else if (k == 144) v = We1[128 * 64 + n];
        W1T[i] = f2bf(v);
    }
    if (i < 64 * 64) {
        const int n = i / 64, k = i % 64;
        W2T[i]  = f2bf(We2[k * 64 + n]);
        Wc1T[i] = f2bf(Wc1[k * 64 + n]);
    }
}

// ---------------------------------------------------------------------------
// Edge pipeline: 64 edges per block, 256 threads (4 waves).
// Wave w computes rows [w*16, w*16+16) of the tile through all 3 GEMMs.
// mfma_f32_16x16x32_bf16; D: col=lane&15, row=(lane>>4)*4+reg  [m89].
// A frag: row=lane&15, k=(lane>>4)*8..+8 ; B frag: col=lane&15, same k.
// ---------------------------------------------------------------------------
__global__ __launch_bounds__(256) void egnn_edge_mfma(
    const float* __restrict__ h, const float* __restrict__ pos,
    const int* __restrict__ ei, const float* __restrict__ ea,
    const short* __restrict__ W1T, const short* __restrict__ W2T,
    const short* __restrict__ Wc1T,
    const float* __restrict__ be1, const float* __restrict__ be2,
    const float* __restrict__ bc1, const float* __restrict__ bc2,
    const float* __restrict__ Wc2,
    float* __restrict__ agg, float* __restrict__ dpos, int E)
{
    __shared__ short As[64][168];   // 21504 B, stride 336B -> 2-way banks (free)
    __shared__ short M1[64][72];    //  9216 B
    __shared__ short M2[64][72];    //  9216 B
    __shared__ float sdir[3][64];   //   768 B
    __shared__ int   sdst[64];      //   256 B   (total 40960 B = 4 blocks/CU)

    const int tid = threadIdx.x;
    const int e0  = blockIdx.x * 64;

    // ---- gather: 4 threads per edge ----
    {
        const int el = tid >> 2;
        const int part = tid & 3;
        const int e = e0 + el;
        if (e < E) {
            const int src = ei[e];
            const int dst = ei[E + e];
            const int node = (part < 2) ? src : dst;
            const float4* hp = reinterpret_cast<const float4*>(
                h + (size_t)node * 64 + (part & 1) * 32);
            #pragma unroll
            for (int q = 0; q < 4; ++q) {
                float4 v0 = hp[2 * q], v1 = hp[2 * q + 1];
                *reinterpret_cast<short8*>(&As[el][part * 32 + q * 8]) = pack8(v0, v1);
            }
            if (part == 0) {
                const float4* eap = reinterpret_cast<const float4*>(ea + (size_t)e * 16);
                #pragma unroll
                for (int q = 0; q < 2; ++q) {
                    float4 v0 = eap[2 * q], v1 = eap[2 * q + 1];
                    *reinterpret_cast<short8*>(&As[el][128 + q * 8]) = pack8(v0, v1);
                }
            } else if (part == 2) {
                const float dx = pos[3 * dst + 0] - pos[3 * src + 0];
                const float dy = pos[3 * dst + 1] - pos[3 * src + 1];
                const float dz = pos[3 * dst + 2] - pos[3 * src + 2];
                const float d2 = fminf(dx * dx + dy * dy + dz * dz, 1000.0f);
                const float inv = 1.0f / sqrtf(d2 + 1e-8f);
                short8 z0 = {f2bf(d2), 0, 0, 0, 0, 0, 0, 0};
                short8 z1 = {0, 0, 0, 0, 0, 0, 0, 0};
                *reinterpret_cast<short8*>(&As[el][144]) = z0;
                *reinterpret_cast<short8*>(&As[el][152]) = z1;
                sdir[0][el] = dx * inv;
                sdir[1][el] = dy * inv;
                sdir[2][el] = dz * inv;
                sdst[el] = dst;
            }
        }
    }
    __syncthreads();

    const int lane = tid & 63;
    const int wave = tid >> 6;
    const int r16  = lane & 15;
    const int kg   = lane >> 4;
    const int mrow = wave * 16 + r16;

    // ---- GEMM1: [64,160] @ [160,64] ----
    f32x4 acc1[4];
    #pragma unroll
    for (int nt = 0; nt < 4; ++nt) {
        const float b = be1[r16 + nt * 16];
        acc1[nt] = {b, b, b, b};
    }
    #pragma unroll
    for (int kt = 0; kt < 5; ++kt) {
        short8 a = *reinterpret_cast<const short8*>(&As[mrow][kt * 32 + kg * 8]);
        #pragma unroll
        for (int nt = 0; nt < 4; ++nt) {
            short8 b = *reinterpret_cast<const short8*>(
                &W1T[(r16 + nt * 16) * 160 + kt * 32 + kg * 8]);
            acc1[nt] = __builtin_amdgcn_mfma_f32_16x16x32_bf16(a, b, acc1[nt], 0, 0, 0);
        }
    }
    #pragma unroll
    for (int nt = 0; nt < 4; ++nt)
        #pragma unroll
        for (int rg = 0; rg < 4; ++rg)
            M1[wave * 16 + kg * 4 + rg][r16 + nt * 16] = f2bf(fmaxf(acc1[nt][rg], 0.0f));
    // M1 rows are wave-private; lgkmcnt ordering suffices (no barrier).

    // ---- GEMM2: [64,64] @ [64,64], keep f32 acc for agg scatter ----
    f32x4 acc2[4];
    #pragma unroll
    for (int nt = 0; nt < 4; ++nt) {
        const float b = be2[r16 + nt * 16];
        acc2[nt] = {b, b, b, b};
    }
    #pragma unroll
    for (int kt = 0; kt < 2; ++kt) {
        short8 a = *reinterpret_cast<const short8*>(&M1[mrow][kt * 32 + kg * 8]);
        #pragma unroll
        for (int nt = 0; nt < 4; ++nt) {
            short8 b = *reinterpret_cast<const short8*>(
                &W2T[(r16 + nt * 16) * 64 + kt * 32 + kg * 8]);
            acc2[nt] = __builtin_amdgcn_mfma_f32_16x16x32_bf16(a, b, acc2[nt], 0, 0, 0);
        }
    }
    #pragma unroll
    for (int nt = 0; nt < 4; ++nt)
        #pragma unroll
        for (int rg = 0; rg < 4; ++rg) {
            const float v = fmaxf(acc2[nt][rg], 0.0f);
            acc2[nt][rg] = v;
            M2[wave * 16 + kg * 4 + rg][r16 + nt * 16] = f2bf(v);
        }

    // ---- GEMM3: coord MLP layer 1 ----
    f32x4 acc3[4];
    #pragma unroll
    for (int nt = 0; nt < 4; ++nt) {
        const float b = bc1[r16 + nt * 16];
        acc3[nt] = {b, b, b, b};
    }
    #pragma unroll
    for (int kt = 0; kt < 2; ++kt) {
        short8 a = *reinterpret_cast<const short8*>(&M2[mrow][kt * 32 + kg * 8]);
        #pragma unroll
        for (int nt = 0; nt < 4; ++nt) {
            short8 b = *reinterpret_cast<const short8*>(
                &Wc1T[(r16 + nt * 16) * 64 + kt * 32 + kg * 8]);
            acc3[nt] = __builtin_amdgcn_mfma_f32_16x16x32_bf16(a, b, acc3[nt], 0, 0, 0);
        }
    }

    // ---- coef = tanh(relu(c) . Wc2 + bc2) * 0.1 ; rows reduce over 16 lanes
    float prt[4] = {0.0f, 0.0f, 0.0f, 0.0f};
    #pragma unroll
    for (int nt = 0; nt < 4; ++nt) {
        const float wv = Wc2[r16 + nt * 16];
        #pragma unroll
        for (int rg = 0; rg < 4; ++rg)
            prt[rg] += fmaxf(acc3[nt][rg], 0.0f) * wv;
    }
    #pragma unroll
    for (int off = 1; off < 16; off <<= 1)
        #pragma unroll
        for (int rg = 0; rg < 4; ++rg)
            prt[rg] += __shfl_xor(prt[rg], off);
    const float bc2v = bc2[0];

    // ---- scatter: dpos (3 lanes per row) ----
    if (r16 < 3) {
        #pragma unroll
        for (int rg = 0; rg < 4; ++rg) {
            const int er = wave * 16 + kg * 4 + rg;
            if (e0 + er < E) {
                const float coef = tanhf(prt[rg] + bc2v) * 0.1f;
                unsafeAtomicAdd(&dpos[3 * sdst[er] + r16], sdir[r16][er] * coef);
            }
        }
    }
    // ---- scatter: agg += m2 ----
    #pragma unroll
    for (int rg = 0; rg < 4; ++rg) {
        const int er = wave * 16 + kg * 4 + rg;
        if (e0 + er < E) {
            float* arow = agg + (size_t)sdst[er] * 64;
            #pragma unroll
            for (int nt = 0; nt < 4; ++nt)
                unsafeAtomicAdd(&arow[r16 + nt * 16], acc2[nt][rg]);
        }
    }
}

// ---------------------------------------------------------------------------
// Node MLP + residual + LayerNorm (unchanged from round 1).
// ---------------------------------------------------------------------------
__global__ __launch_bounds__(256) void egnn_node(
    const float* __restrict__ h, const float* __restrict__ pos,
    const float* __restrict__ agg, const float* __restrict__ dpos,
    const float* __restrict__ Wn, const float* __restrict__ bn,
    const float* __restrict__ lng, const float* __restrict__ lnb,
    float* __restrict__ h_out, float* __restrict__ pos_out, int N)
{
    __shared__ float sW[128 * 64];
    for (int i = threadIdx.x; i < (128 * 64) / 4; i += 256)
        reinterpret_cast<float4*>(sW)[i] = reinterpret_cast<const float4*>(Wn)[i];
    __syncthreads();

    const int lane = threadIdx.x & 63;
    const int wid  = threadIdx.x >> 6;
    const float bnl = bn[lane];
    const float g   = lng[lane];
    const float bb  = lnb[lane];

    for (int i = blockIdx.x * 4 + wid; i < N; i += gridDim.x * 4) {
        const float xh = h[(size_t)i * 64 + lane];
        const float xa = agg[(size_t)i * 64 + lane];
        float acc = bnl;
        #pragma unroll 8
        for (int k = 0; k < 64; ++k)
            acc = fmaf(__shfl(xh, k), sW[k * 64 + lane], acc);
        #pragma unroll 8
        for (int k = 0; k < 64; ++k)
            acc = fmaf(__shfl(xa, k), sW[(64 + k) * 64 + lane], acc);

        const float x = xh + fmaxf(acc, 0.0f);
        float s = x;
        #pragma unroll
        for (int off = 32; off > 0; off >>= 1) s += __shfl_xor(s, off);
        const float mu = s * 0.015625f;
        const float d = x - mu;
        float v = d * d;
        #pragma unroll
        for (int off = 32; off > 0; off >>= 1) v += __shfl_xor(v, off);
        v *= 0.015625f;
        const float ho = d * rsqrtf(v + 1e-5f) * g + bb;
        h_out[(size_t)i * 64 + lane] = ho;

        if (lane < 3) {
            pos_out[(size_t)i * 3 + lane] =
                pos[(size_t)i * 3 + lane] + dpos[(size_t)i * 3 + lane];
        }
    }
}

extern "C" void kernel_launch(void* const* d_in, const int* in_sizes, int n_in,
                              void* d_out, int out_size, void* d_ws, size_t ws_size,
                              hipStream_t stream)
{
    const float* h   = (const float*)d_in[0];
    const float* pos = (const float*)d_in[1];
    const int*   ei  = (const int*)d_in[2];
    const float* ea  = (const float*)d_in[3];
    const float* We1 = (const float*)d_in[4];
    const float* be1 = (const float*)d_in[5];
    const float* We2 = (const float*)d_in[6];
    const float* be2 = (const float*)d_in[7];
    const float* Wc1 = (const float*)d_in[8];
    const float* bc1 = (const float*)d_in[9];
    const float* Wc2 = (const float*)d_in[10];
    const float* bc2 = (const float*)d_in[11];
    const float* Wn  = (const float*)d_in[12];
    const float* bn  = (const float*)d_in[13];
    const float* lng = (const float*)d_in[14];
    const float* lnb = (const float*)d_in[15];

    const int N = in_sizes[0] / 64;
    const int E = in_sizes[2] / 2;

    float* agg  = (float*)d_ws;                        // [N,64]
    float* dpos = agg + (size_t)N * 64;                // [N,3]
    short* W1T  = (short*)(dpos + (size_t)N * 3);      // [64,160] bf16
    short* W2T  = W1T + 64 * 160;                      // [64,64]
    short* Wc1T = W2T + 64 * 64;                       // [64,64]

    hipMemsetAsync(d_ws, 0, (size_t)N * 67 * sizeof(float), stream);
    convert_weights<<<40, 256, 0, stream>>>(We1, We2, Wc1, W1T, W2T, Wc1T);

    float* h_out   = (float*)d_out;                    // [N,64]
    float* pos_out = h_out + (size_t)N * 64;           // [N,3]

    egnn_edge_mfma<<<(E + 63) / 64, 256, 0, stream>>>(
        h, pos, ei, ea, W1T, W2T, Wc1T, be1, be2, bc1, bc2, Wc2, agg, dpos, E);
    egnn_node<<<2048, 256, 0, stream>>>(h, pos, agg, dpos, Wn, bn, lng, lnb,
                                        h_out, pos_out, N);
}

// Round 3
// 510.231 us; speedup vs baseline: 11.9304x; 1.3959x over previous
//
#include <hip/hip_runtime.h>

using f32x4  = __attribute__((ext_vector_type(4))) float;
using short8 = __attribute__((ext_vector_type(8))) short;

__device__ inline short f2bf(float x) {
    union { float f; unsigned u; } v; v.f = x;
    unsigned r = v.u + 0x7fffu + ((v.u >> 16) & 1u);   // RNE
    return (short)(r >> 16);
}

__device__ inline short8 pack8(float4 a, float4 b) {
    short8 r;
    r[0] = f2bf(a.x); r[1] = f2bf(a.y); r[2] = f2bf(a.z); r[3] = f2bf(a.w);
    r[4] = f2bf(b.x); r[5] = f2bf(b.y); r[6] = f2bf(b.z); r[7] = f2bf(b.w);
    return r;
}

__device__ inline void atomic_pk_add_bf16(short* addr, unsigned pk) {
    asm volatile("global_atomic_pk_add_bf16 %0, %1, off"
                 :: "v"(addr), "v"(pk) : "memory");
}

// ---------------------------------------------------------------------------
// Weight prep: f32 -> bf16 transposed. Layer-1 K permuted:
// k 0..127 = h_src,h_dst; 128..143 = ea (orig rows 129..144); 144 = dist2
// (orig row 128); 145..159 = zero pad. Also WnT[64][128] for node MLP.
// ---------------------------------------------------------------------------
__global__ __launch_bounds__(256) void convert_weights(
    const float* __restrict__ We1, const float* __restrict__ We2,
    const float* __restrict__ Wc1, const float* __restrict__ Wn,
    short* __restrict__ W1T, short* __restrict__ W2T,
    short* __restrict__ Wc1T, short* __restrict__ WnT)
{
    const int i = blockIdx.x * 256 + threadIdx.x;
    if (i < 64 * 160) {
        const int n = i / 160, k = i % 160;
        float v = 0.0f;
        if (k < 128)       v = We1[k * 64 + n];
        else if (k < 144)  v = We1[(129 + k - 128) * 64 + n];
        else if (k == 144) v = We1[128 * 64 + n];
        W1T[i] = f2bf(v);
    }
    if (i < 64 * 128) {
        const int n = i / 128, k = i % 128;
        WnT[i] = f2bf(Wn[k * 64 + n]);
    }
    if (i < 64 * 64) {
        const int n = i / 64, k = i % 64;
        W2T[i]  = f2bf(We2[k * 64 + n]);
        Wc1T[i] = f2bf(Wc1[k * 64 + n]);
    }
}

__global__ __launch_bounds__(256) void convert_h(
    const float* __restrict__ h, short* __restrict__ hb, int n8)
{
    const int i = blockIdx.x * 256 + threadIdx.x;
    if (i < n8) {
        const float4* h4 = reinterpret_cast<const float4*>(h);
        reinterpret_cast<short8*>(hb)[i] = pack8(h4[2 * i], h4[2 * i + 1]);
    }
}

// ---------------------------------------------------------------------------
// Edge pipeline: 64 edges/block, 4 waves. LDS = 22.5 KB -> 7 blocks/CU.
// M1/M2 overlaid into As (wave-private rows, strictly read-then-write;
// per-wave in-order LDS pipe guarantees ordering).
// mfma_f32_16x16x32_bf16; D: col=lane&15, row=(lane>>4)*4+reg  [m89].
// ---------------------------------------------------------------------------
__global__ __launch_bounds__(256) void egnn_edge_mfma(
    const short* __restrict__ hb, const float* __restrict__ pos,
    const int* __restrict__ ei, const float* __restrict__ ea,
    const short* __restrict__ W1T, const short* __restrict__ W2T,
    const short* __restrict__ Wc1T,
    const float* __restrict__ be1, const float* __restrict__ be2,
    const float* __restrict__ bc1, const float* __restrict__ bc2,
    const float* __restrict__ Wc2,
    short* __restrict__ aggb, float* __restrict__ dpos, int E)
{
    __shared__ short As[64][168];   // 21504 B; M1 -> cols 0..64, M2 -> 64..128
    __shared__ float sdir[3][64];
    __shared__ int   sdst[64];      // total 22528 B -> 7 blocks/CU

    const int tid = threadIdx.x;
    const int e0  = blockIdx.x * 64;

    // ---- gather: 4 threads/edge, bf16 h copied raw (no conversion) ----
    {
        const int el = tid >> 2, part = tid & 3;
        const int e = e0 + el;
        if (e < E) {
            const int src = ei[e];
            const int dst = ei[E + e];
            const int node = (part < 2) ? src : dst;
            const short8* hp = reinterpret_cast<const short8*>(
                hb + (size_t)node * 64 + (part & 1) * 32);
            #pragma unroll
            for (int q = 0; q < 4; ++q)
                *reinterpret_cast<short8*>(&As[el][part * 32 + q * 8]) = hp[q];
            if (part == 0) {
                const float4* eap = reinterpret_cast<const float4*>(ea + (size_t)e * 16);
                #pragma unroll
                for (int q = 0; q < 2; ++q)
                    *reinterpret_cast<short8*>(&As[el][128 + q * 8]) =
                        pack8(eap[2 * q], eap[2 * q + 1]);
            } else if (part == 2) {
                const float dx = pos[3 * dst + 0] - pos[3 * src + 0];
                const float dy = pos[3 * dst + 1] - pos[3 * src + 1];
                const float dz = pos[3 * dst + 2] - pos[3 * src + 2];
                const float d2 = fminf(dx * dx + dy * dy + dz * dz, 1000.0f);
                const float inv = 1.0f / sqrtf(d2 + 1e-8f);
                short8 z0 = {f2bf(d2), 0, 0, 0, 0, 0, 0, 0};
                *reinterpret_cast<short8*>(&As[el][144]) = z0;
                sdir[0][el] = dx * inv;
                sdir[1][el] = dy * inv;
                sdir[2][el] = dz * inv;
                sdst[el] = dst;
            } else if (part == 3) {
                short8 z = {0, 0, 0, 0, 0, 0, 0, 0};
                *reinterpret_cast<short8*>(&As[el][152]) = z;
            }
        }
    }
    __syncthreads();

    const int lane = tid & 63;
    const int wave = tid >> 6;
    const int r16  = lane & 15;
    const int kg   = lane >> 4;
    const int mrow = wave * 16 + r16;

    // ---- GEMM1: [64,160] @ [160,64] ----
    f32x4 acc1[4];
    #pragma unroll
    for (int nt = 0; nt < 4; ++nt) {
        const float b = be1[r16 + nt * 16];
        acc1[nt] = {b, b, b, b};
    }
    #pragma unroll
    for (int kt = 0; kt < 5; ++kt) {
        short8 a = *reinterpret_cast<const short8*>(&As[mrow][kt * 32 + kg * 8]);
        #pragma unroll
        for (int nt = 0; nt < 4; ++nt) {
            short8 b = *reinterpret_cast<const short8*>(
                &W1T[(r16 + nt * 16) * 160 + kt * 32 + kg * 8]);
            acc1[nt] = __builtin_amdgcn_mfma_f32_16x16x32_bf16(a, b, acc1[nt], 0, 0, 0);
        }
    }
    // M1 -> As cols 0..64 (own wave's rows only; all GEMM1 reads already issued)
    #pragma unroll
    for (int nt = 0; nt < 4; ++nt)
        #pragma unroll
        for (int rg = 0; rg < 4; ++rg)
            As[wave * 16 + kg * 4 + rg][r16 + nt * 16] = f2bf(fmaxf(acc1[nt][rg], 0.0f));

    // ---- GEMM2: keep f32 acc for agg scatter ----
    f32x4 acc2[4];
    #pragma unroll
    for (int nt = 0; nt < 4; ++nt) {
        const float b = be2[r16 + nt * 16];
        acc2[nt] = {b, b, b, b};
    }
    #pragma unroll
    for (int kt = 0; kt < 2; ++kt) {
        short8 a = *reinterpret_cast<const short8*>(&As[mrow][kt * 32 + kg * 8]);
        #pragma unroll
        for (int nt = 0; nt < 4; ++nt) {
            short8 b = *reinterpret_cast<const short8*>(
                &W2T[(r16 + nt * 16) * 64 + kt * 32 + kg * 8]);
            acc2[nt] = __builtin_amdgcn_mfma_f32_16x16x32_bf16(a, b, acc2[nt], 0, 0, 0);
        }
    }
    // M2 -> As cols 64..128
    #pragma unroll
    for (int nt = 0; nt < 4; ++nt)
        #pragma unroll
        for (int rg = 0; rg < 4; ++rg) {
            const float v = fmaxf(acc2[nt][rg], 0.0f);
            acc2[nt][rg] = v;
            As[wave * 16 + kg * 4 + rg][64 + r16 + nt * 16] = f2bf(v);
        }

    // ---- GEMM3: coord MLP layer 1 ----
    f32x4 acc3[4];
    #pragma unroll
    for (int nt = 0; nt < 4; ++nt) {
        const float b = bc1[r16 + nt * 16];
        acc3[nt] = {b, b, b, b};
    }
    #pragma unroll
    for (int kt = 0; kt < 2; ++kt) {
        short8 a = *reinterpret_cast<const short8*>(&As[mrow][64 + kt * 32 + kg * 8]);
        #pragma unroll
        for (int nt = 0; nt < 4; ++nt) {
            short8 b = *reinterpret_cast<const short8*>(
                &Wc1T[(r16 + nt * 16) * 64 + kt * 32 + kg * 8]);
            acc3[nt] = __builtin_amdgcn_mfma_f32_16x16x32_bf16(a, b, acc3[nt], 0, 0, 0);
        }
    }

    // ---- coef = tanh(relu(c) . Wc2 + bc2) * 0.1 ----
    float prt[4] = {0.0f, 0.0f, 0.0f, 0.0f};
    #pragma unroll
    for (int nt = 0; nt < 4; ++nt) {
        const float wv = Wc2[r16 + nt * 16];
        #pragma unroll
        for (int rg = 0; rg < 4; ++rg)
            prt[rg] += fmaxf(acc3[nt][rg], 0.0f) * wv;
    }
    #pragma unroll
    for (int off = 1; off < 16; off <<= 1)
        #pragma unroll
        for (int rg = 0; rg < 4; ++rg)
            prt[rg] += __shfl_xor(prt[rg], off);
    const float bc2v = bc2[0];

    // ---- scatter: dpos (f32 atomics, 3 lanes per edge row) ----
    if (r16 < 3) {
        #pragma unroll
        for (int rg = 0; rg < 4; ++rg) {
            const int er = wave * 16 + kg * 4 + rg;
            if (e0 + er < E) {
                const float coef = tanhf(prt[rg] + bc2v) * 0.1f;
                unsafeAtomicAdd(&dpos[3 * sdst[er] + r16], sdir[r16][er] * coef);
            }
        }
    }
    // ---- scatter: agg += m2 via packed-bf16 atomics (2 cols/op) ----
    #pragma unroll
    for (int rg = 0; rg < 4; ++rg) {
        const int er = wave * 16 + kg * 4 + rg;
        if (e0 + er < E) {
            short* arow = aggb + (size_t)sdst[er] * 64;
            #pragma unroll
            for (int nt = 0; nt < 4; ++nt) {
                const float v  = acc2[nt][rg];
                const float vp = __shfl_xor(v, 1);
                if ((r16 & 1) == (nt >> 1)) {   // even lanes: nt 0,1; odd: nt 2,3
                    const int col0 = (r16 & ~1) + nt * 16;
                    const unsigned blo = (unsigned short)f2bf((r16 & 1) ? vp : v);
                    const unsigned bhi = (unsigned short)f2bf((r16 & 1) ? v : vp);
                    atomic_pk_add_bf16(arow + col0, blo | (bhi << 16));
                }
            }
        }
    }
}

// ---------------------------------------------------------------------------
// Node MLP + residual + LayerNorm, MFMA version. 64 nodes/block, 4 waves.
// ---------------------------------------------------------------------------
__global__ __launch_bounds__(256) void egnn_node_mfma(
    const float* __restrict__ h, const short* __restrict__ hb,
    const short* __restrict__ aggb, const float* __restrict__ pos,
    const float* __restrict__ dpos, const short* __restrict__ WnT,
    const float* __restrict__ bn, const float* __restrict__ lng,
    const float* __restrict__ lnb,
    float* __restrict__ h_out, float* __restrict__ pos_out, int N)
{
    __shared__ short As[64][136];   // cols 0..64 = h (bf16), 64..128 = agg
    const int tid = threadIdx.x;
    const int n0  = blockIdx.x * 64;

    // pos_out = pos + dpos
    if (tid < 64) {
        const int n = n0 + tid;
        if (n < N) {
            #pragma unroll
            for (int c = 0; c < 3; ++c)
                pos_out[(size_t)3 * n + c] = pos[(size_t)3 * n + c] + dpos[(size_t)3 * n + c];
        }
    }

    {   // stage [h | agg] rows (sequential -> coalesced)
        const int row = tid >> 2, part = tid & 3;
        const int n = n0 + row;
        if (n < N) {
            const short* sp = (part < 2) ? (hb + (size_t)n * 64 + (part & 1) * 32)
                                         : (aggb + (size_t)n * 64 + (part & 1) * 32);
            #pragma unroll
            for (int q = 0; q < 4; ++q)
                *reinterpret_cast<short8*>(&As[row][part * 32 + q * 8]) =
                    *reinterpret_cast<const short8*>(sp + q * 8);
        }
    }
    __syncthreads();

    const int lane = tid & 63;
    const int wave = tid >> 6;
    const int r16  = lane & 15;
    const int kg   = lane >> 4;
    const int mrow = wave * 16 + r16;

    f32x4 acc[4];
    #pragma unroll
    for (int nt = 0; nt < 4; ++nt) {
        const float b = bn[r16 + nt * 16];
        acc[nt] = {b, b, b, b};
    }
    #pragma unroll
    for (int kt = 0; kt < 4; ++kt) {
        short8 a = *reinterpret_cast<const short8*>(&As[mrow][kt * 32 + kg * 8]);
        #pragma unroll
        for (int nt = 0; nt < 4; ++nt) {
            short8 b = *reinterpret_cast<const short8*>(
                &WnT[(r16 + nt * 16) * 128 + kt * 32 + kg * 8]);
            acc[nt] = __builtin_amdgcn_mfma_f32_16x16x32_bf16(a, b, acc[nt], 0, 0, 0);
        }
    }

    // x = h + relu(acc), residual from f32 h
    float xv[4][4];
    #pragma unroll
    for (int rg = 0; rg < 4; ++rg) {
        const int n = n0 + wave * 16 + kg * 4 + rg;
        const bool ok = n < N;
        #pragma unroll
        for (int nt = 0; nt < 4; ++nt)
            xv[nt][rg] = (ok ? h[(size_t)n * 64 + r16 + nt * 16] : 0.0f)
                         + fmaxf(acc[nt][rg], 0.0f);
    }

    float g[4], bb[4];
    #pragma unroll
    for (int nt = 0; nt < 4; ++nt) { g[nt] = lng[r16 + nt * 16]; bb[nt] = lnb[r16 + nt * 16]; }

    #pragma unroll
    for (int rg = 0; rg < 4; ++rg) {
        float s = xv[0][rg] + xv[1][rg] + xv[2][rg] + xv[3][rg];
        #pragma unroll
        for (int off = 1; off < 16; off <<= 1) s += __shfl_xor(s, off);
        const float mu = s * 0.015625f;
        float q = 0.0f;
        #pragma unroll
        for (int nt = 0; nt < 4; ++nt) { const float d = xv[nt][rg] - mu; q += d * d; }
        #pragma unroll
        for (int off = 1; off < 16; off <<= 1) q += __shfl_xor(q, off);
        const float inv = rsqrtf(q * 0.015625f + 1e-5f);
        const int n = n0 + wave * 16 + kg * 4 + rg;
        if (n < N) {
            #pragma unroll
            for (int nt = 0; nt < 4; ++nt)
                h_out[(size_t)n * 64 + r16 + nt * 16] =
                    (xv[nt][rg] - mu) * inv * g[nt] + bb[nt];
        }
    }
}

extern "C" void kernel_launch(void* const* d_in, const int* in_sizes, int n_in,
                              void* d_out, int out_size, void* d_ws, size_t ws_size,
                              hipStream_t stream)
{
    const float* h   = (const float*)d_in[0];
    const float* pos = (const float*)d_in[1];
    const int*   ei  = (const int*)d_in[2];
    const float* ea  = (const float*)d_in[3];
    const float* We1 = (const float*)d_in[4];
    const float* be1 = (const float*)d_in[5];
    const float* We2 = (const float*)d_in[6];
    const float* be2 = (const float*)d_in[7];
    const float* Wc1 = (const float*)d_in[8];
    const float* bc1 = (const float*)d_in[9];
    const float* Wc2 = (const float*)d_in[10];
    const float* bc2 = (const float*)d_in[11];
    const float* Wn  = (const float*)d_in[12];
    const float* bn  = (const float*)d_in[13];
    const float* lng = (const float*)d_in[14];
    const float* lnb = (const float*)d_in[15];

    const int N = in_sizes[0] / 64;
    const int E = in_sizes[2] / 2;

    // workspace layout
    short* aggb = (short*)d_ws;                         // [N,64] bf16
    float* dpos = (float*)(aggb + (size_t)N * 64);      // [N,3]  f32
    short* W1T  = (short*)(dpos + (size_t)N * 3);       // [64,160]
    short* W2T  = W1T + 64 * 160;                       // [64,64]
    short* Wc1T = W2T + 64 * 64;                        // [64,64]
    short* WnT  = Wc1T + 64 * 64;                       // [64,128]
    short* hbuf = WnT + 64 * 128;                       // [N,64] bf16

    hipMemsetAsync(d_ws, 0, (size_t)N * 140, stream);   // aggb + dpos
    convert_weights<<<40, 256, 0, stream>>>(We1, We2, Wc1, Wn, W1T, W2T, Wc1T, WnT);
    convert_h<<<(N * 64 / 8 + 255) / 256, 256, 0, stream>>>(h, hbuf, N * 64 / 8);

    float* h_out   = (float*)d_out;
    float* pos_out = h_out + (size_t)N * 64;

    egnn_edge_mfma<<<(E + 63) / 64, 256, 0, stream>>>(
        hbuf, pos, ei, ea, W1T, W2T, Wc1T, be1, be2, bc1, bc2, Wc2, aggb, dpos, E);
    egnn_node_mfma<<<(N + 63) / 64, 256, 0, stream>>>(
        h, hbuf, aggb, pos, dpos, WnT, bn, lng, lnb, h_out, pos_out, N);
}